// Round 7
// baseline (87.143 us; speedup 1.0000x reference)
//
#include <hip/hip_runtime.h>
#include <math.h>

constexpr int NB = 16;    // batch
constexpr int SL = 1024;  // L
constexpr int ND = 128;   // D
constexpr int NH = 256;   // H
constexpr int SPAD = 544; // padded spectrum/time length (17*32)

// bf16 plane layout in ws (ushort element indices)
constexpr size_t PLANE  = (size_t)NB * ND * SPAD;   // 1,114,112 elems
constexpr size_t CS_OFF = 0;                        // cs  [b][d][s]
constexpr size_t DD_OFF = PLANE;                    // dd  [b][d][s]
constexpr size_t FR_OFF = 2 * PLANE;                // Frw [b][d][k]
constexpr size_t FI_OFF = 3 * PLANE;                // Fiw [b][d][k]
// float scratch after the 4 bf16 planes (float element indices)
constexpr size_t F32B      = 2 * PLANE;             // 4 planes * 2B = 2*PLANE floats
constexpr size_t P_OFF     = F32B;                  // [2][16][16][128]
constexpr size_t SCALE_OFF = P_OFF + 2 * 16 * 16 * 128;
constexpr size_t BIAS_OFF  = SCALE_OFF + NB * ND;

constexpr float TWO_PI = 6.283185307179586f;

typedef float          f32x4 __attribute__((ext_vector_type(4)));
typedef unsigned int   u32x4 __attribute__((ext_vector_type(4)));
typedef unsigned short u16x8 __attribute__((ext_vector_type(8)));

__device__ __forceinline__ unsigned short f2bf(float f) {
    unsigned u = __float_as_uint(f);
    return (unsigned short)((u + 0x7FFFu + ((u >> 16) & 1u)) >> 16);
}
__device__ __forceinline__ void mfma16(f32x4& acc, u32x4 a, u32x4 b) {
    asm("v_mfma_f32_16x16x32_bf16 %0, %1, %2, %0" : "+v"(acc) : "v"(a), "v"(b));
}

// ---------------- K1: partial sums of y and z over t ----------------
__global__ __launch_bounds__(256) void k_partial(const float* __restrict__ y,
                                                 const float* __restrict__ z,
                                                 float* __restrict__ ws) {
    const int blk = blockIdx.x;          // 512 = src*256 + b*16 + ch
    const int ch  = blk & 15;
    const int b   = (blk >> 4) & 15;
    const int src = blk >> 8;
    const float* base = (src == 0 ? y : z) + (size_t)b * SL * ND;
    const int d    = threadIdx.x & 127;
    const int half = threadIdx.x >> 7;
    float s = 0.f;
    const int t0 = ch * 64 + half;
    for (int j = 0; j < 32; ++j)
        s += base[(size_t)(t0 + 2 * j) * ND + d];
    __shared__ float red[256];
    red[threadIdx.x] = s;
    __syncthreads();
    if (half == 0)
        ws[P_OFF + ((size_t)((src * NB + b) * 16 + ch)) * ND + d] = s + red[d + 128];
}

// ---------------- K2: MLPs -> scale/bias ----------------
__global__ __launch_bounds__(256) void k_mlp(
    float* __restrict__ ws,
    const int* __restrict__ len_y, const int* __restrict__ len_z,
    const float* __restrict__ W1w1, const float* __restrict__ W1b1,
    const float* __restrict__ W1w2, const float* __restrict__ W1b2,
    const float* __restrict__ B1w1, const float* __restrict__ B1b1,
    const float* __restrict__ B1w2, const float* __restrict__ B1b2,
    const float* __restrict__ W2w1, const float* __restrict__ W2b1,
    const float* __restrict__ W2w2, const float* __restrict__ W2b2,
    const float* __restrict__ B2w1, const float* __restrict__ B2b1,
    const float* __restrict__ B2w2, const float* __restrict__ B2b2) {
    const int b = blockIdx.x;
    const int tid = threadIdx.x;
    __shared__ float c1[ND], c2[ND];
    __shared__ float h[4][NH];
    __shared__ float o[4][ND];

    if (tid < ND) {
        float s = 0.f;
        for (int ch = 0; ch < 16; ++ch)
            s += ws[P_OFF + ((size_t)((0 * NB + b) * 16 + ch)) * ND + tid];
        c1[tid] = s / (float)len_y[b];
    } else {
        const int d = tid - ND;
        float s = 0.f;
        for (int ch = 0; ch < 16; ++ch)
            s += ws[P_OFF + ((size_t)((1 * NB + b) * 16 + ch)) * ND + d];
        c2[d] = s / (float)len_z[b];
    }
    __syncthreads();

    const float* w1s[4] = {W1w1, B1w1, W2w1, B2w1};
    const float* b1s[4] = {W1b1, B1b1, W2b1, B2b1};
    const float* w2s[4] = {W1w2, B1w2, W2w2, B2w2};
    const float* b2s[4] = {W1b2, B1b2, W2b2, B2b2};

    for (int m = 0; m < 4; ++m) {
        const float* c = (m < 2) ? c1 : c2;
        const float* w = w1s[m];
        const int j = tid;
        float s = b1s[m][j];
        for (int i = 0; i < ND; ++i)
            s = fmaf(c[i], w[i * NH + j], s);
        h[m][j] = 0.5f * s * (1.f + erff(s * 0.7071067811865475f));
    }
    __syncthreads();

    for (int p = tid; p < 4 * ND; p += 256) {
        const int m = p >> 7, d = p & 127;
        const float* w = w2s[m];
        float s = b2s[m][d];
        for (int j = 0; j < NH; ++j)
            s = fmaf(h[m][j], w[j * ND + d], s);
        o[m][d] = s;
    }
    __syncthreads();

    if (tid < ND) {
        ws[SCALE_OFF + b * ND + tid] = 1.f + 0.5f * (o[0][tid] + o[2][tid]);
        ws[BIAS_OFF  + b * ND + tid] = 0.5f * (o[1][tid] + o[3][tid]);
    }
}

// ---------------- K3: fold x -> cs/dd bf16 planes [b][d][s] ----------------
// grid (17, NB), 256 thr: thread = (d = tid&127, slot = tid>>7); covers 32 s per block.
__global__ __launch_bounds__(256) void k_prep(const float* __restrict__ x,
                                              const int* __restrict__ len_x,
                                              unsigned short* __restrict__ wsb) {
    const int b = blockIdx.y;
    const int l = len_x[b];
    const int NS = (l >> 1) + 1;
    const int d = threadIdx.x & 127;
    const int slot = threadIdx.x >> 7;
#pragma unroll
    for (int it = 0; it < 2; ++it) {
        const int sb = (blockIdx.x * 4 + slot * 2 + it) * 8;
        u16x8 cb, db;
#pragma unroll
        for (int j = 0; j < 8; ++j) {
            const int s = sb + j;
            float c = 0.f, dd = 0.f;
            if (s < NS) {
                const float a = x[((size_t)b * SL + s) * ND + d];
                float p = 0.f;
                if (s > 0 && 2 * s != l) p = x[((size_t)b * SL + (l - s)) * ND + d];
                c = a + p; dd = a - p;
            }
            cb[j] = f2bf(c); db[j] = f2bf(dd);
        }
        const size_t ro = ((size_t)b * ND + d) * SPAD + sb;
        *(u16x8*)&wsb[CS_OFF + ro] = cb;
        *(u16x8*)&wsb[DD_OFF + ro] = db;
    }
}

// ---------------- K4: forward DFT via MFMA + filter -> Frw/Fiw planes ----------------
// grid (33 ktiles, NB), 256 thr = 4 waves; wave w: d in [32w, 32w+32), k-tile shared (16).
// X^T[d,k]: re = sum_s cs[d,s]*cos(th k s); im = sum_s dd[d,s]*(-sin(th k s))
__global__ __launch_bounds__(256) void k_fwd(const int* __restrict__ len_x,
                                             const float* __restrict__ wsf,
                                             unsigned short* __restrict__ wsb) {
    const int b = blockIdx.y;
    const int l = len_x[b];
    const int NS = (l >> 1) + 1;
    const int kbase = blockIdx.x * 16;
    if (kbase >= NS) return;
    const float invl = 1.f / (float)l;
    const float fl = (float)l;

    __shared__ __align__(16) unsigned short Ec[16][40];
    __shared__ __align__(16) unsigned short Es[16][40];

    const int tid = threadIdx.x;
    const int lane = tid & 63, wave = tid >> 6;
    const int dbase = wave * 32;
    const int lrow = lane & 15, lkg = lane >> 4;

    f32x4 accR[2], accI[2];
#pragma unroll
    for (int t = 0; t < 2; ++t) {
        accR[t] = 0.f; accI[t] = 0.f;
    }

    for (int s0 = 0; s0 < NS; s0 += 32) {
        __syncthreads();
#pragma unroll
        for (int pp = 0; pp < 2; ++pp) {
            const int p = tid + pp * 256;
            const int kk = p >> 5, ss = p & 31;
            const int sg = s0 + ss;
            float cv = 0.f, sv = 0.f;
            if (sg < NS) {
                const float ks = (float)((kbase + kk) * sg);
                const float q = floorf(ks * invl);
                const float idxf = fmaf(-fl, q, ks);     // (k*s) mod l  (maybe -l off: ok)
                float s_, c_;
                sincosf(-TWO_PI * idxf * invl, &s_, &c_); // c_=cos, s_=-sin
                cv = c_; sv = s_;
            }
            Ec[kk][ss] = f2bf(cv);
            Es[kk][ss] = f2bf(sv);
        }
        __syncthreads();

        const u32x4 eC = *(const u32x4*)&Ec[lrow][lkg * 8];
        const u32x4 eS = *(const u32x4*)&Es[lrow][lkg * 8];
#pragma unroll
        for (int t = 0; t < 2; ++t) {
            const int drow = dbase + t * 16 + lrow;
            const size_t ro = ((size_t)b * ND + drow) * SPAD + s0 + lkg * 8;
            const u32x4 aC = *(const u32x4*)&wsb[CS_OFF + ro];
            const u32x4 aD = *(const u32x4*)&wsb[DD_OFF + ro];
            mfma16(accR[t], aC, eC);
            mfma16(accI[t], aD, eS);
        }
    }

    const int kcol = kbase + lrow;
    if (kcol >= NS) return;
    const float w = (kcol == 0 || 2 * kcol == l) ? 1.f : 2.f;
#pragma unroll
    for (int t = 0; t < 2; ++t) {
#pragma unroll
        for (int r = 0; r < 4; ++r) {
            const int drow = dbase + t * 16 + lkg * 4 + r;
            const float sc = wsf[SCALE_OFF + b * ND + drow];
            const float bi = wsf[BIAS_OFF + b * ND + drow];
            const size_t o = ((size_t)b * ND + drow) * SPAD + kcol;
            wsb[FR_OFF + o] = f2bf(w * fmaf(accR[t][r], sc, bi));
            wsb[FI_OFF + o] = f2bf(w * accI[t][r] * sc);
        }
    }
}

// ---------------- K5: inverse DFT via MFMA, t-folded real output + tail zeroing ----
// grid (64 ttiles, NB), 256 thr = 4 waves.
// Blocks with tbase < NS: A[t,d] = sum_k E2c[t,k]*Frw[k,d]; B[t,d] = sum_k E2s[t,k]*Fiw[k,d]
//   out[t] = (A-B)/l ; out[l-t] = (A+B)/l
// Blocks with tbase >= NS: zero any row in [tbase, tbase+16) with row >= l.
__global__ __launch_bounds__(256) void k_inv(const int* __restrict__ len_x,
                                             const unsigned short* __restrict__ wsb,
                                             float* __restrict__ out) {
    const int b = blockIdx.y;
    const int l = len_x[b];
    const int NS = (l >> 1) + 1;
    const int tbase = blockIdx.x * 16;
    const int tid = threadIdx.x;

    if (tbase >= NS) {
        // tail zeroing: rows >= l are not written by any fold partner
        const int row = tbase + (tid >> 4);
        if (row >= l && row < SL) {
            const int c = tid & 15;
            float4 zz = make_float4(0.f, 0.f, 0.f, 0.f);
            float* p = &out[((size_t)b * SL + row) * ND];
            *(float4*)&p[c * 4] = zz;
            *(float4*)&p[(c + 16) * 4] = zz;
        }
        return;
    }

    const float invl = 1.f / (float)l;
    const float fl = (float)l;

    __shared__ __align__(16) unsigned short E2c[16][40];
    __shared__ __align__(16) unsigned short E2s[16][40];

    const int lane = tid & 63, wave = tid >> 6;
    const int dbase = wave * 32;
    const int lrow = lane & 15, lkg = lane >> 4;

    f32x4 accA[2], accB[2];
#pragma unroll
    for (int t = 0; t < 2; ++t) {
        accA[t] = 0.f; accB[t] = 0.f;
    }

    for (int k0 = 0; k0 < NS; k0 += 32) {
        __syncthreads();
#pragma unroll
        for (int pp = 0; pp < 2; ++pp) {
            const int p = tid + pp * 256;
            const int tt = p >> 5, kk = p & 31;
            const int kg = k0 + kk;
            float cv = 0.f, sv = 0.f;
            if (kg < NS) {
                const float tk = (float)((tbase + tt) * kg);
                const float q = floorf(tk * invl);
                const float idxf = fmaf(-fl, q, tk);
                float s_, c_;
                sincosf(TWO_PI * idxf * invl, &s_, &c_);  // +sin
                cv = c_; sv = s_;
            }
            E2c[tt][kk] = f2bf(cv);
            E2s[tt][kk] = f2bf(sv);
        }
        __syncthreads();

        const u32x4 aC = *(const u32x4*)&E2c[lrow][lkg * 8];
        const u32x4 aS = *(const u32x4*)&E2s[lrow][lkg * 8];
#pragma unroll
        for (int t = 0; t < 2; ++t) {
            const int dcol = dbase + t * 16 + lrow;
            const size_t ro = ((size_t)b * ND + dcol) * SPAD + k0 + lkg * 8;
            const u32x4 bR = *(const u32x4*)&wsb[FR_OFF + ro];
            const u32x4 bI = *(const u32x4*)&wsb[FI_OFF + ro];
            mfma16(accA[t], aC, bR);
            mfma16(accB[t], aS, bI);
        }
    }

#pragma unroll
    for (int t = 0; t < 2; ++t) {
#pragma unroll
        for (int r = 0; r < 4; ++r) {
            const int trow = tbase + lkg * 4 + r;
            if (trow >= NS) continue;
            const int dcol = dbase + t * 16 + lrow;
            const float vA = accA[t][r], vB = accB[t][r];
            out[((size_t)b * SL + trow) * ND + dcol] = (vA - vB) * invl;
            if (trow > 0 && 2 * trow != l)
                out[((size_t)b * SL + (l - trow)) * ND + dcol] = (vA + vB) * invl;
        }
    }
}

extern "C" void kernel_launch(void* const* d_in, const int* in_sizes, int n_in,
                              void* d_out, int out_size, void* d_ws, size_t ws_size,
                              hipStream_t stream) {
    const float* x = (const float*)d_in[0];
    const float* y = (const float*)d_in[1];
    const float* z = (const float*)d_in[2];
    const int* len_x = (const int*)d_in[3];
    const int* len_y = (const int*)d_in[4];
    const int* len_z = (const int*)d_in[5];
    float* wsf = (float*)d_ws;
    unsigned short* wsb = (unsigned short*)d_ws;
    float* out = (float*)d_out;

    k_partial<<<512, 256, 0, stream>>>(y, z, wsf);

    k_mlp<<<NB, 256, 0, stream>>>(wsf, len_y, len_z,
        (const float*)d_in[6],  (const float*)d_in[7],  (const float*)d_in[8],  (const float*)d_in[9],
        (const float*)d_in[10], (const float*)d_in[11], (const float*)d_in[12], (const float*)d_in[13],
        (const float*)d_in[14], (const float*)d_in[15], (const float*)d_in[16], (const float*)d_in[17],
        (const float*)d_in[18], (const float*)d_in[19], (const float*)d_in[20], (const float*)d_in[21]);

    k_prep<<<dim3(17, NB), 256, 0, stream>>>(x, len_x, wsb);

    k_fwd<<<dim3(33, NB), 256, 0, stream>>>(len_x, wsf, wsb);

    k_inv<<<dim3(64, NB), 256, 0, stream>>>(len_x, wsb, out);
}